// Round 5
// baseline (31437.674 us; speedup 1.0000x reference)
//
#include <hip/hip_runtime.h>
#include <math.h>

#define B_  32
#define S_  64
#define T_  48
#define V_  32000
#define E_  512
#define H_  1024
#define G3  3072   // 3*H

typedef __attribute__((ext_vector_type(8))) short short8;   // 8 bf16 (4 VGPRs)
typedef __attribute__((ext_vector_type(4))) float f32x4;    // MFMA 16x16 accumulator

__device__ __forceinline__ ushort f2bf(float x) {           // RNE f32 -> bf16
    unsigned u = __float_as_uint(x);
    return (ushort)((u + 0x7FFF + ((u >> 16) & 1)) >> 16);
}
__device__ __forceinline__ void cvt4(float4 v, ushort4& h, ushort4& l) {
    ushort h0 = f2bf(v.x), h1 = f2bf(v.y), h2 = f2bf(v.z), h3 = f2bf(v.w);
    l.x = f2bf(v.x - __uint_as_float((unsigned)h0 << 16));
    l.y = f2bf(v.y - __uint_as_float((unsigned)h1 << 16));
    l.z = f2bf(v.z - __uint_as_float((unsigned)h2 << 16));
    l.w = f2bf(v.w - __uint_as_float((unsigned)h3 << 16));
    h.x = h0; h.y = h1; h.z = h2; h.w = h3;
}

// ---------------------------------------------------------------------------
// Hand-rolled grid barrier (graph-capturable, multi-XCD safe).
// All NB blocks call this the same number of times. cnt zeroed before launch.
// __syncthreads drains each block's stores to its L2 (vmcnt(0) semantics);
// agent-scope release fence writes XCD L2 back to LLC; acquire fence after
// the spin invalidates stale L1/L2 before subsequent reads.
// ---------------------------------------------------------------------------
__device__ __forceinline__ void gsync(unsigned* cnt, unsigned nb, unsigned& tgt) {
    __syncthreads();
    __builtin_amdgcn_fence(__ATOMIC_RELEASE, "agent");
    if (threadIdx.x == 0) {
        __hip_atomic_fetch_add(cnt, 1u, __ATOMIC_RELAXED, __HIP_MEMORY_SCOPE_AGENT);
        tgt += nb;
        while (__hip_atomic_load(cnt, __ATOMIC_RELAXED, __HIP_MEMORY_SCOPE_AGENT) < tgt)
            __builtin_amdgcn_s_sleep(1);
    }
    __syncthreads();
    __builtin_amdgcn_fence(__ATOMIC_ACQUIRE, "agent");
}

// ---------------------------------------------------------------------------
// bf16 split-3 MFMA GEMM:  C[m][n] = sum_k A[m][k]*W[n][k] (+bias[n]), fp32 io.
// (unchanged from round 2 -- correct, absmax-anchored)
// ---------------------------------------------------------------------------
__global__ __launch_bounds__(256)
void gemm_mfma(const float* __restrict__ A, int lda,
               const int* __restrict__ ids, int id_mode,  // 0 none, 1 enc b*64+t, 2 dec b*48+t
               const float* __restrict__ W, int ldw,
               const float* __restrict__ bias,
               float* __restrict__ C, int out_mode, int ldc,
               int M, int K)
{
    __shared__ __align__(16) ushort AhS[128][40];
    __shared__ __align__(16) ushort AlS[128][40];
    __shared__ __align__(16) ushort BhS[128][40];
    __shared__ __align__(16) ushort BlS[128][40];

    const int tid = threadIdx.x;
    const int n0  = blockIdx.x * 128;
    const int m0  = blockIdx.y * 128;
    const int sr  = tid >> 1;
    const int sk  = (tid & 1) * 16;

    long abase;
    {
        int m = m0 + sr;
        if (id_mode == 0) {
            abase = (long)m * lda;
        } else {
            int t = m >> 5, b = m & 31;
            int idx = (id_mode == 1) ? (b * S_ + t) : (b * T_ + t);
            abase = (long)ids[idx] * lda;
        }
    }
    const float* Ar = A + abase + sk;
    const float* Wr = W + (long)(n0 + sr) * ldw + sk;

    const int lane = tid & 63;
    const int wv   = tid >> 6;
    const int wr   = (wv >> 1) * 64;
    const int wc   = (wv & 1) * 64;
    const int lr   = lane & 15;
    const int lk   = (lane >> 4) * 8;

    f32x4 acc[4][4];
    const f32x4 fz = {0.f, 0.f, 0.f, 0.f};
#pragma unroll
    for (int i = 0; i < 4; ++i)
#pragma unroll
        for (int j = 0; j < 4; ++j) acc[i][j] = fz;

    for (int k0 = 0; k0 < K; k0 += 32) {
        float4 a4[4], w4[4];
#pragma unroll
        for (int q = 0; q < 4; ++q) {
            a4[q] = *(const float4*)(Ar + k0 + q * 4);
            w4[q] = *(const float4*)(Wr + k0 + q * 4);
        }
        __syncthreads();
#pragma unroll
        for (int q = 0; q < 4; ++q) {
            ushort4 h, l;
            cvt4(a4[q], h, l);
            *(ushort4*)&AhS[sr][sk + q * 4] = h;
            *(ushort4*)&AlS[sr][sk + q * 4] = l;
            cvt4(w4[q], h, l);
            *(ushort4*)&BhS[sr][sk + q * 4] = h;
            *(ushort4*)&BlS[sr][sk + q * 4] = l;
        }
        __syncthreads();

        short8 fah[4], fbh[4];
#pragma unroll
        for (int i = 0; i < 4; ++i) {
            fah[i] = *(const short8*)&AhS[wr + i * 16 + lr][lk];
            fbh[i] = *(const short8*)&BhS[wc + i * 16 + lr][lk];
        }
#pragma unroll
        for (int i = 0; i < 4; ++i)
#pragma unroll
            for (int j = 0; j < 4; ++j)
                acc[i][j] = __builtin_amdgcn_mfma_f32_16x16x32_bf16(fah[i], fbh[j], acc[i][j], 0, 0, 0);
        {
            short8 fal[4];
#pragma unroll
            for (int i = 0; i < 4; ++i)
                fal[i] = *(const short8*)&AlS[wr + i * 16 + lr][lk];
#pragma unroll
            for (int i = 0; i < 4; ++i)
#pragma unroll
                for (int j = 0; j < 4; ++j)
                    acc[i][j] = __builtin_amdgcn_mfma_f32_16x16x32_bf16(fal[i], fbh[j], acc[i][j], 0, 0, 0);
        }
        {
            short8 fbl[4];
#pragma unroll
            for (int j = 0; j < 4; ++j)
                fbl[j] = *(const short8*)&BlS[wc + j * 16 + lr][lk];
#pragma unroll
            for (int i = 0; i < 4; ++i)
#pragma unroll
                for (int j = 0; j < 4; ++j)
                    acc[i][j] = __builtin_amdgcn_mfma_f32_16x16x32_bf16(fah[i], fbl[j], acc[i][j], 0, 0, 0);
        }
    }

    float bcol[4] = {0.f, 0.f, 0.f, 0.f};
    if (bias) {
#pragma unroll
        for (int j = 0; j < 4; ++j) bcol[j] = bias[n0 + wc + j * 16 + lr];
    }
    const int rbase = (lane >> 4) * 4;
#pragma unroll
    for (int i = 0; i < 4; ++i) {
#pragma unroll
        for (int r = 0; r < 4; ++r) {
            int m = m0 + wr + i * 16 + rbase + r;
            float* crow;
            if (out_mode == 0) {
                crow = C + (long)m * ldc;
            } else {
                if (m >= M) continue;
                int t = m >> 5, b2 = m & 31;
                crow = C + (long)b2 * ((T_ - 1) * V_) + (long)t * V_;
            }
#pragma unroll
            for (int j = 0; j < 4; ++j)
                crow[n0 + wc + j * 16 + lr] = acc[i][j][r] + bcol[j];
        }
    }
}

// ---------------------------------------------------------------------------
// GRU phase body (2 output units per block). 256 thr = (b 0..31) x (ks 0..7).
// sm: >= 2*3*8*32 floats (redh); if HAS_X, >= 2*2*3*8*32 (redh+redx).
// ---------------------------------------------------------------------------
template<int HAS_X, int HAS_GI>
__device__ __forceinline__ void gru_phase(
    float* sm, int j0,
    const float* __restrict__ x, int xld,
    const float* __restrict__ wx, int wxld, int wxoff,
    const float* __restrict__ bih,
    const float* __restrict__ gi_pre,   // row stride G3, rows = b (bias included)
    const float* __restrict__ h,
    const float* __restrict__ whh,
    const float* __restrict__ bhh,
    float* __restrict__ h_new,
    float* __restrict__ seq_out, long seq_stride)
{
    const int tid = threadIdx.x;
    const int b   = tid & 31;
    const int ks  = tid >> 5;
    float* redh = sm;                    // [2][3][8][32]
    float* redx = sm + 2 * 3 * 8 * 32;

    const float* hr  = h + (long)b * H_;
    const float* wh  = whh + (long)j0 * H_;
    const float* xr  = nullptr;
    const float* wxb = nullptr;
    if (HAS_X) {
        xr  = x + (long)b * xld;
        wxb = wx + (long)j0 * wxld + wxoff;
    }

    float ah[2][3] = {};
    float ax[2][3] = {};
    const int k0 = ks * 128;
#pragma unroll 2
    for (int k = k0; k < k0 + 128; k += 4) {
        float4 hv = *(const float4*)(hr + k);
        float4 xv;
        if (HAS_X) xv = *(const float4*)(xr + k);
#pragma unroll
        for (int u = 0; u < 2; ++u) {
#pragma unroll
            for (int g = 0; g < 3; ++g) {
                float4 wv = *(const float4*)(wh + ((long)g * H_ + u) * H_ + k);
                ah[u][g] += hv.x*wv.x + hv.y*wv.y + hv.z*wv.z + hv.w*wv.w;
                if (HAS_X) {
                    float4 uv = *(const float4*)(wxb + ((long)g * H_ + u) * wxld + k);
                    ax[u][g] += xv.x*uv.x + xv.y*uv.y + xv.z*uv.z + xv.w*uv.w;
                }
            }
        }
    }
#pragma unroll
    for (int u = 0; u < 2; ++u)
#pragma unroll
        for (int g = 0; g < 3; ++g) {
            redh[((u * 3 + g) * 8 + ks) * 32 + b] = ah[u][g];
            if (HAS_X) redx[((u * 3 + g) * 8 + ks) * 32 + b] = ax[u][g];
        }
    __syncthreads();
    if (tid < 64) {
        const int u  = tid >> 5;
        const int bb = tid & 31;
        const int j  = j0 + u;
        float gh0 = bhh[j], gh1 = bhh[H_ + j], gh2 = bhh[2*H_ + j];
#pragma unroll
        for (int q = 0; q < 8; ++q) {
            gh0 += redh[((u * 3 + 0) * 8 + q) * 32 + bb];
            gh1 += redh[((u * 3 + 1) * 8 + q) * 32 + bb];
            gh2 += redh[((u * 3 + 2) * 8 + q) * 32 + bb];
        }
        float gi0, gi1, gi2;
        if (HAS_GI) {
            const float* g = gi_pre + (long)bb * G3;
            gi0 = g[j]; gi1 = g[H_ + j]; gi2 = g[2*H_ + j];
        } else {
            gi0 = bih[j]; gi1 = bih[H_ + j]; gi2 = bih[2*H_ + j];
        }
        if (HAS_X) {
#pragma unroll
            for (int q = 0; q < 8; ++q) {
                gi0 += redx[((u * 3 + 0) * 8 + q) * 32 + bb];
                gi1 += redx[((u * 3 + 1) * 8 + q) * 32 + bb];
                gi2 += redx[((u * 3 + 2) * 8 + q) * 32 + bb];
            }
        }
        float r = 1.f / (1.f + expf(-(gi0 + gh0)));
        float z = 1.f / (1.f + expf(-(gi1 + gh1)));
        float n = tanhf(gi2 + r * gh2);
        float hv = h[(long)bb * H_ + j];
        float o = (1.f - z) * n + z * hv;
        h_new[(long)bb * H_ + j] = o;
        if (seq_out) seq_out[(long)bb * seq_stride + j] = o;
    }
}

// ---------------------------------------------------------------------------
// Persistent encoder layer: T GRU steps with hand-rolled grid barrier.
// Regular launch (graph-capturable). Grid 512 x 256 = exactly 2 blocks/CU.
// ---------------------------------------------------------------------------
__global__ __launch_bounds__(256, 2)
void enc_loop(const float* __restrict__ gi, const float* __restrict__ whh,
              const float* __restrict__ bhh,
              float* __restrict__ ha, float* __restrict__ hb,
              float* __restrict__ seq, long t_stride, long b_stride, int T,
              unsigned* cnt)
{
    __shared__ float sm[2 * 3 * 8 * 32];
    const int j0 = blockIdx.x * 2;
    float* h[2] = { ha, hb };
    unsigned tgt = 0;
    int p = 0;
    for (int t = 0; t < T; ++t) {
        gru_phase<0, 1>(sm, j0, nullptr, 0, nullptr, 0, 0, nullptr,
                        gi + (long)t * B_ * G3,
                        h[p], whh, bhh, h[1 - p],
                        seq + (long)t * t_stride, b_stride);
        gsync(cnt, 512, tgt);
        p ^= 1;
    }
}

// ---------------------------------------------------------------------------
// Persistent decoder: 47 steps of {scores, softmax+ctx, gru0, gru1}.
// Regular launch. Grid 512 x 256.
// ---------------------------------------------------------------------------
__global__ __launch_bounds__(256, 2)
void dec_loop(const float* __restrict__ proj, const float* __restrict__ enc_out,
              const int* __restrict__ src_ids, const float* __restrict__ gi_dec,
              const float* __restrict__ wih0, const float* __restrict__ whh0,
              const float* __restrict__ bhh0,
              const float* __restrict__ wih1, const float* __restrict__ bih1,
              const float* __restrict__ whh1, const float* __restrict__ bhh1,
              float* __restrict__ cat,
              float* __restrict__ h0a, float* __restrict__ h0b,
              float* __restrict__ h1a, float* __restrict__ h1b,
              float* __restrict__ scores, unsigned* cnt)
{
    __shared__ float sm[2 * 2 * 3 * 8 * 32];   // 12 KB, gru phases
    __shared__ float at[S_];
    __shared__ float red4[4][64];
    float* h0[2] = { h0a, h0b };
    float* h1[2] = { h1a, h1b };
    const int blk = blockIdx.x, tid = threadIdx.x;
    unsigned tgt = 0;
    int p = 0;
    for (int t = 0; t < T_ - 1; ++t) {
        // ---- A1: scores[b][s] = proj[b,s,:] . d1[b,:]  (16 blocks/b, 4 s each)
        {
            const int b    = blk >> 4;
            const int s    = ((blk & 15) << 2) + (tid >> 6);
            const int lane = tid & 63;
            const float* pr = proj + ((long)b * S_ + s) * H_;
            const float* dr = h1[p] + (long)b * H_;
            float a = 0.f;
#pragma unroll
            for (int c = 0; c < 4; ++c) {
                float4 pv = *(const float4*)(pr + c * 256 + lane * 4);
                float4 dv = *(const float4*)(dr + c * 256 + lane * 4);
                a += pv.x*dv.x + pv.y*dv.y + pv.z*dv.z + pv.w*dv.w;
            }
#pragma unroll
            for (int off = 32; off > 0; off >>= 1) a += __shfl_xor(a, off);
            if (lane == 0)
                scores[b * S_ + s] = (src_ids[b * S_ + s] != 0) ? a : -1e9f;
        }
        gsync(cnt, 512, tgt);
        // ---- A2: softmax (redundant per block) + ctx 64-h slice
        {
            const int b  = blk >> 4;
            const int hs = (blk & 15) * 64;
            if (tid < 64) {
                float v = scores[b * S_ + tid];
                float mx = v;
#pragma unroll
                for (int off = 32; off > 0; off >>= 1) mx = fmaxf(mx, __shfl_xor(mx, off));
                float e = expf(v - mx);
                float smm = e;
#pragma unroll
                for (int off = 32; off > 0; off >>= 1) smm += __shfl_xor(smm, off);
                at[tid] = e / smm;
            }
            __syncthreads();
            const int h  = hs + (tid & 63);
            const int sg = tid >> 6;
            const float* eb = enc_out + (long)b * S_ * H_ + h;
            float a = 0.f;
            for (int s = sg * 16; s < sg * 16 + 16; ++s)
                a += at[s] * eb[(long)s * H_];
            red4[sg][tid & 63] = a;
            __syncthreads();
            if (tid < 64)
                cat[(long)t * B_ * 2048 + (long)b * 2048 + H_ + hs + tid] =
                    red4[0][tid] + red4[1][tid] + red4[2][tid] + red4[3][tid];
        }
        gsync(cnt, 512, tgt);
        // ---- C: gru0 (x = ctx, gi precomputed)
        gru_phase<1, 1>(sm, blk * 2,
                        cat + (long)t * B_ * 2048 + H_, 2048,
                        wih0, E_ + H_, E_, nullptr,
                        gi_dec + (long)t * B_ * G3,
                        h0[p], whh0, bhh0, h0[1 - p], nullptr, 0);
        gsync(cnt, 512, tgt);
        // ---- D: gru1 (x = h0_new), write d1 into cat row
        gru_phase<1, 0>(sm, blk * 2,
                        h0[1 - p], H_,
                        wih1, H_, 0, bih1, nullptr,
                        h1[p], whh1, bhh1, h1[1 - p],
                        cat + (long)t * B_ * 2048, 2048);
        gsync(cnt, 512, tgt);
        p ^= 1;
    }
}

// ---------------------------------------------------------------------------
extern "C" void kernel_launch(void* const* d_in, const int* in_sizes, int n_in,
                              void* d_out, int out_size, void* d_ws, size_t ws_size,
                              hipStream_t stream)
{
    (void)in_sizes; (void)n_in; (void)out_size; (void)ws_size;
    const int*   src_ids  = (const int*)  d_in[0];
    const int*   tgt_ids  = (const int*)  d_in[2];
    const float* enc_emb  = (const float*)d_in[3];
    const float* dec_emb  = (const float*)d_in[4];
    const float* enc_wih0 = (const float*)d_in[5];
    const float* enc_whh0 = (const float*)d_in[6];
    const float* enc_bih0 = (const float*)d_in[7];
    const float* enc_bhh0 = (const float*)d_in[8];
    const float* enc_wih1 = (const float*)d_in[9];
    const float* enc_whh1 = (const float*)d_in[10];
    const float* enc_bih1 = (const float*)d_in[11];
    const float* enc_bhh1 = (const float*)d_in[12];
    const float* dec_wih0 = (const float*)d_in[13];
    const float* dec_whh0 = (const float*)d_in[14];
    const float* dec_bih0 = (const float*)d_in[15];
    const float* dec_bhh0 = (const float*)d_in[16];
    const float* dec_wih1 = (const float*)d_in[17];
    const float* dec_whh1 = (const float*)d_in[18];
    const float* dec_bih1 = (const float*)d_in[19];
    const float* dec_bhh1 = (const float*)d_in[20];
    const float* attn_w   = (const float*)d_in[21];
    const float* out_w    = (const float*)d_in[22];
    const float* out_b    = (const float*)d_in[23];
    float* out = (float*)d_out;

    // workspace layout (floats)
    float* ws      = (float*)d_ws;
    float* gi_enc0 = ws;                         // 2048*3072 (reused as gi_enc1)
    float* gi_dec  = gi_enc0 + 2048L * G3;       // 1536*3072
    float* enc_out = gi_dec  + 1536L * G3;       // 2048*1024  [b][t][h]
    float* proj    = enc_out + 2048L * H_;       // 2048*1024  [b][s][h]
    float* cat     = proj    + 2048L * H_;       // 1536*2048  row m=t*32+b: [d1 | ctx]
    float* states  = cat     + 1536L * 2048;     // 4*32*1024
    unsigned* cnts = (unsigned*)(states + 4L * B_ * H_);  // 64 u32 (3 slots, 64B apart)
    float* scores  = (float*)(cnts + 64);        // 32*64
    float* h0a = states;
    float* h0b = states + 1L * B_ * H_;
    float* h1a = states + 2L * B_ * H_;
    float* h1b = states + 3L * B_ * H_;
    float* enc_l0  = cat;                        // alias: layer-0 seq [t][b][h], free pre-decoder

    // zero states + sync counters (re-zeroed on every graph replay)
    hipMemsetAsync(states, 0, (4L * B_ * H_ + 64) * sizeof(float), stream);

    // batched input-to-hidden GEMMs (embedding gather fused)
    gemm_mfma<<<dim3(24, 16), 256, 0, stream>>>(enc_emb, E_, src_ids, 1, enc_wih0, E_, enc_bih0,
                                                gi_enc0, 0, G3, 2048, E_);
    gemm_mfma<<<dim3(24, 12), 256, 0, stream>>>(dec_emb, E_, tgt_ids, 2, dec_wih0, E_ + H_, dec_bih0,
                                                gi_dec, 0, G3, 1536, E_);

    // ---- encoder layer 0 (persistent, 64 steps in one launch) ----
    enc_loop<<<512, 256, 0, stream>>>(gi_enc0, enc_whh0, enc_bhh0, h0a, h0b,
                                      enc_l0, (long)B_ * H_, (long)H_, S_, cnts + 0);

    // batched layer-1 input GEMM: gi_enc1 = enc_l0 @ wih1.T  (overwrites gi_enc0)
    gemm_mfma<<<dim3(24, 16), 256, 0, stream>>>(enc_l0, H_, nullptr, 0, enc_wih1, H_, enc_bih1,
                                                gi_enc0, 0, G3, 2048, H_);

    // ---- encoder layer 1 (persistent) ----
    enc_loop<<<512, 256, 0, stream>>>(gi_enc0, enc_whh1, enc_bhh1, h1a, h1b,
                                      enc_out, (long)H_, (long)S_ * H_, S_, cnts + 16);

    // proj = enc_out @ attn_w.T   (M=2048, N=1024, K=1024)
    gemm_mfma<<<dim3(8, 16), 256, 0, stream>>>(enc_out, H_, nullptr, 0, attn_w, H_, nullptr,
                                               proj, 0, H_, 2048, H_);

    // ---- decoder (persistent, all 47 steps in one launch) ----
    dec_loop<<<512, 256, 0, stream>>>(proj, enc_out, src_ids, gi_dec,
                                      dec_wih0, dec_whh0, dec_bhh0,
                                      dec_wih1, dec_bih1, dec_whh1, dec_bhh1,
                                      cat, h0a, h0b, h1a, h1b, scores, cnts + 32);

    // ---- output projection: out = cat @ out_w.T + out_b ----
    gemm_mfma<<<dim3(V_ / 128, 12), 256, 0, stream>>>(cat, 2048, nullptr, 0, out_w, 2048, out_b,
                                                      out, 1, 0, 1504, 2048);
}

// Round 6
// 13069.917 us; speedup vs baseline: 2.4053x; 2.4053x over previous
//
#include <hip/hip_runtime.h>
#include <math.h>

#define B_  32
#define S_  64
#define T_  48
#define V_  32000
#define E_  512
#define H_  1024
#define G3  3072   // 3*H

typedef __attribute__((ext_vector_type(8))) short short8;   // 8 bf16 (4 VGPRs)
typedef __attribute__((ext_vector_type(4))) float f32x4;    // MFMA 16x16 accumulator

__device__ __forceinline__ ushort f2bf(float x) {           // RNE f32 -> bf16
    unsigned u = __float_as_uint(x);
    return (ushort)((u + 0x7FFF + ((u >> 16) & 1)) >> 16);
}
__device__ __forceinline__ void cvt4(float4 v, ushort4& h, ushort4& l) {
    ushort h0 = f2bf(v.x), h1 = f2bf(v.y), h2 = f2bf(v.z), h3 = f2bf(v.w);
    l.x = f2bf(v.x - __uint_as_float((unsigned)h0 << 16));
    l.y = f2bf(v.y - __uint_as_float((unsigned)h1 << 16));
    l.z = f2bf(v.z - __uint_as_float((unsigned)h2 << 16));
    l.w = f2bf(v.w - __uint_as_float((unsigned)h3 << 16));
    h.x = h0; h.y = h1; h.z = h2; h.w = h3;
}

// ---------------------------------------------------------------------------
// Coherent (agent-scope, write-through-to-LLC) scalar store. Used for ALL
// intra-kernel cross-block data. Discipline: each such address is written
// exactly once per dispatch, before any read -> readers may use normal
// cached loads (no stale copies can exist; dispatch-start acquire wipes
// L1/L2 between graph replays). This replaces cache-wide fences entirely.
// ---------------------------------------------------------------------------
__device__ __forceinline__ void coh_store(float* p, float v) {
    __hip_atomic_store((unsigned*)p, __float_as_uint(v),
                       __ATOMIC_RELAXED, __HIP_MEMORY_SCOPE_AGENT);
}

// ---------------------------------------------------------------------------
// Fence-free grid barrier. __syncthreads drains vmcnt(0) (so all coh_stores
// have reached the LLC) before thread0 signals arrival via an agent-scope
// atomic (served at the coherent point). No buffer_wbl2 / buffer_inv.
// ---------------------------------------------------------------------------
__device__ __forceinline__ void gsync(unsigned* cnt, unsigned nb, unsigned& tgt) {
    __syncthreads();
    if (threadIdx.x == 0) {
        __hip_atomic_fetch_add(cnt, 1u, __ATOMIC_RELAXED, __HIP_MEMORY_SCOPE_AGENT);
        tgt += nb;
        while (__hip_atomic_load(cnt, __ATOMIC_RELAXED, __HIP_MEMORY_SCOPE_AGENT) < tgt)
            __builtin_amdgcn_s_sleep(2);
    }
    __syncthreads();
}

// ---------------------------------------------------------------------------
// bf16 split-3 MFMA GEMM:  C[m][n] = sum_k A[m][k]*W[n][k] (+bias[n]), fp32 io.
// (unchanged -- correct, absmax-anchored)
// ---------------------------------------------------------------------------
__global__ __launch_bounds__(256)
void gemm_mfma(const float* __restrict__ A, int lda,
               const int* __restrict__ ids, int id_mode,  // 0 none, 1 enc b*64+t, 2 dec b*48+t
               const float* __restrict__ W, int ldw,
               const float* __restrict__ bias,
               float* __restrict__ C, int out_mode, int ldc,
               int M, int K)
{
    __shared__ __align__(16) ushort AhS[128][40];
    __shared__ __align__(16) ushort AlS[128][40];
    __shared__ __align__(16) ushort BhS[128][40];
    __shared__ __align__(16) ushort BlS[128][40];

    const int tid = threadIdx.x;
    const int n0  = blockIdx.x * 128;
    const int m0  = blockIdx.y * 128;
    const int sr  = tid >> 1;
    const int sk  = (tid & 1) * 16;

    long abase;
    {
        int m = m0 + sr;
        if (id_mode == 0) {
            abase = (long)m * lda;
        } else {
            int t = m >> 5, b = m & 31;
            int idx = (id_mode == 1) ? (b * S_ + t) : (b * T_ + t);
            abase = (long)ids[idx] * lda;
        }
    }
    const float* Ar = A + abase + sk;
    const float* Wr = W + (long)(n0 + sr) * ldw + sk;

    const int lane = tid & 63;
    const int wv   = tid >> 6;
    const int wr   = (wv >> 1) * 64;
    const int wc   = (wv & 1) * 64;
    const int lr   = lane & 15;
    const int lk   = (lane >> 4) * 8;

    f32x4 acc[4][4];
    const f32x4 fz = {0.f, 0.f, 0.f, 0.f};
#pragma unroll
    for (int i = 0; i < 4; ++i)
#pragma unroll
        for (int j = 0; j < 4; ++j) acc[i][j] = fz;

    for (int k0 = 0; k0 < K; k0 += 32) {
        float4 a4[4], w4[4];
#pragma unroll
        for (int q = 0; q < 4; ++q) {
            a4[q] = *(const float4*)(Ar + k0 + q * 4);
            w4[q] = *(const float4*)(Wr + k0 + q * 4);
        }
        __syncthreads();
#pragma unroll
        for (int q = 0; q < 4; ++q) {
            ushort4 h, l;
            cvt4(a4[q], h, l);
            *(ushort4*)&AhS[sr][sk + q * 4] = h;
            *(ushort4*)&AlS[sr][sk + q * 4] = l;
            cvt4(w4[q], h, l);
            *(ushort4*)&BhS[sr][sk + q * 4] = h;
            *(ushort4*)&BlS[sr][sk + q * 4] = l;
        }
        __syncthreads();

        short8 fah[4], fbh[4];
#pragma unroll
        for (int i = 0; i < 4; ++i) {
            fah[i] = *(const short8*)&AhS[wr + i * 16 + lr][lk];
            fbh[i] = *(const short8*)&BhS[wc + i * 16 + lr][lk];
        }
#pragma unroll
        for (int i = 0; i < 4; ++i)
#pragma unroll
            for (int j = 0; j < 4; ++j)
                acc[i][j] = __builtin_amdgcn_mfma_f32_16x16x32_bf16(fah[i], fbh[j], acc[i][j], 0, 0, 0);
        {
            short8 fal[4];
#pragma unroll
            for (int i = 0; i < 4; ++i)
                fal[i] = *(const short8*)&AlS[wr + i * 16 + lr][lk];
#pragma unroll
            for (int i = 0; i < 4; ++i)
#pragma unroll
                for (int j = 0; j < 4; ++j)
                    acc[i][j] = __builtin_amdgcn_mfma_f32_16x16x32_bf16(fal[i], fbh[j], acc[i][j], 0, 0, 0);
        }
        {
            short8 fbl[4];
#pragma unroll
            for (int j = 0; j < 4; ++j)
                fbl[j] = *(const short8*)&BlS[wc + j * 16 + lr][lk];
#pragma unroll
            for (int i = 0; i < 4; ++i)
#pragma unroll
                for (int j = 0; j < 4; ++j)
                    acc[i][j] = __builtin_amdgcn_mfma_f32_16x16x32_bf16(fah[i], fbl[j], acc[i][j], 0, 0, 0);
        }
    }

    float bcol[4] = {0.f, 0.f, 0.f, 0.f};
    if (bias) {
#pragma unroll
        for (int j = 0; j < 4; ++j) bcol[j] = bias[n0 + wc + j * 16 + lr];
    }
    const int rbase = (lane >> 4) * 4;
#pragma unroll
    for (int i = 0; i < 4; ++i) {
#pragma unroll
        for (int r = 0; r < 4; ++r) {
            int m = m0 + wr + i * 16 + rbase + r;
            float* crow;
            if (out_mode == 0) {
                crow = C + (long)m * ldc;
            } else {
                if (m >= M) continue;
                int t = m >> 5, b2 = m & 31;
                crow = C + (long)b2 * ((T_ - 1) * V_) + (long)t * V_;
            }
#pragma unroll
            for (int j = 0; j < 4; ++j)
                crow[n0 + wc + j * 16 + lr] = acc[i][j][r] + bcol[j];
        }
    }
}

// ---------------------------------------------------------------------------
// GRU phase body (2 output units per block). 256 thr = (b 0..31) x (ks 0..7).
// h read from h + b*h_ld (normal cached loads, write-once addresses);
// h' written coherently to h_new + b*hn_ld (+ optional out2 + b*o2_ld).
// ---------------------------------------------------------------------------
template<int HAS_X, int HAS_GI>
__device__ __forceinline__ void gru_phase(
    float* sm, int j0,
    const float* __restrict__ x, long xld,
    const float* __restrict__ wx, int wxld, int wxoff,
    const float* __restrict__ bih,
    const float* __restrict__ gi_pre,   // row stride G3, rows = b (bias included)
    const float* __restrict__ h, long h_ld,
    const float* __restrict__ whh,
    const float* __restrict__ bhh,
    float* __restrict__ h_new, long hn_ld,
    float* __restrict__ out2, long o2_ld)
{
    const int tid = threadIdx.x;
    const int b   = tid & 31;
    const int ks  = tid >> 5;
    float* redh = sm;                    // [2][3][8][32]
    float* redx = sm + 2 * 3 * 8 * 32;

    const float* hr  = h + (long)b * h_ld;
    const float* wh  = whh + (long)j0 * H_;
    const float* xr  = nullptr;
    const float* wxb = nullptr;
    if (HAS_X) {
        xr  = x + (long)b * xld;
        wxb = wx + (long)j0 * wxld + wxoff;
    }

    float ah[2][3] = {};
    float ax[2][3] = {};
    const int k0 = ks * 128;
#pragma unroll 2
    for (int k = k0; k < k0 + 128; k += 4) {
        float4 hv = *(const float4*)(hr + k);
        float4 xv;
        if (HAS_X) xv = *(const float4*)(xr + k);
#pragma unroll
        for (int u = 0; u < 2; ++u) {
#pragma unroll
            for (int g = 0; g < 3; ++g) {
                float4 wv = *(const float4*)(wh + ((long)g * H_ + u) * H_ + k);
                ah[u][g] += hv.x*wv.x + hv.y*wv.y + hv.z*wv.z + hv.w*wv.w;
                if (HAS_X) {
                    float4 uv = *(const float4*)(wxb + ((long)g * H_ + u) * wxld + k);
                    ax[u][g] += xv.x*uv.x + xv.y*uv.y + xv.z*uv.z + xv.w*uv.w;
                }
            }
        }
    }
#pragma unroll
    for (int u = 0; u < 2; ++u)
#pragma unroll
        for (int g = 0; g < 3; ++g) {
            redh[((u * 3 + g) * 8 + ks) * 32 + b] = ah[u][g];
            if (HAS_X) redx[((u * 3 + g) * 8 + ks) * 32 + b] = ax[u][g];
        }
    __syncthreads();
    if (tid < 64) {
        const int u  = tid >> 5;
        const int bb = tid & 31;
        const int j  = j0 + u;
        float gh0 = bhh[j], gh1 = bhh[H_ + j], gh2 = bhh[2*H_ + j];
#pragma unroll
        for (int q = 0; q < 8; ++q) {
            gh0 += redh[((u * 3 + 0) * 8 + q) * 32 + bb];
            gh1 += redh[((u * 3 + 1) * 8 + q) * 32 + bb];
            gh2 += redh[((u * 3 + 2) * 8 + q) * 32 + bb];
        }
        float gi0, gi1, gi2;
        if (HAS_GI) {
            const float* g = gi_pre + (long)bb * G3;
            gi0 = g[j]; gi1 = g[H_ + j]; gi2 = g[2*H_ + j];
        } else {
            gi0 = bih[j]; gi1 = bih[H_ + j]; gi2 = bih[2*H_ + j];
        }
        if (HAS_X) {
#pragma unroll
            for (int q = 0; q < 8; ++q) {
                gi0 += redx[((u * 3 + 0) * 8 + q) * 32 + bb];
                gi1 += redx[((u * 3 + 1) * 8 + q) * 32 + bb];
                gi2 += redx[((u * 3 + 2) * 8 + q) * 32 + bb];
            }
        }
        float r = 1.f / (1.f + expf(-(gi0 + gh0)));
        float z = 1.f / (1.f + expf(-(gi1 + gh1)));
        float n = tanhf(gi2 + r * gh2);
        float hv = h[(long)bb * h_ld + j];
        float o = (1.f - z) * n + z * hv;
        coh_store(&h_new[(long)bb * hn_ld + j], o);
        if (out2) coh_store(&out2[(long)bb * o2_ld + j], o);
    }
}

// ---------------------------------------------------------------------------
// Persistent encoder layer: T GRU steps, fence-free barrier, h chained
// through the (write-once) seq buffer itself. Grid 512 x 256.
// seq[t] at seq + t*t_stride, rows stride b_stride.
// ---------------------------------------------------------------------------
__global__ __launch_bounds__(256, 2)
void enc_loop(const float* __restrict__ gi, const float* __restrict__ whh,
              const float* __restrict__ bhh,
              const float* __restrict__ h0init,
              float* __restrict__ seq, long t_stride, long b_stride,
              float* __restrict__ h_final, int T, unsigned* cnt)
{
    __shared__ float sm[2 * 3 * 8 * 32];
    const int j0 = blockIdx.x * 2;
    unsigned tgt = 0;
    for (int t = 0; t < T; ++t) {
        const float* hp = t ? seq + (long)(t - 1) * t_stride : h0init;
        long hld        = t ? b_stride : (long)H_;
        gru_phase<0, 1>(sm, j0, nullptr, 0, nullptr, 0, 0, nullptr,
                        gi + (long)t * B_ * G3,
                        hp, hld, whh, bhh,
                        seq + (long)t * t_stride, b_stride,
                        (t == T - 1) ? h_final : nullptr, H_);
        if (t < T - 1) gsync(cnt, 512, tgt);
    }
}

// ---------------------------------------------------------------------------
// Persistent decoder: 47 steps of {scores, softmax+ctx, gru0, gru1}.
// All cross-phase state rotated per-step (write-once) + coh stores.
// Grid 512 x 256.
// ---------------------------------------------------------------------------
__global__ __launch_bounds__(256, 2)
void dec_loop(const float* __restrict__ proj, const float* __restrict__ enc_out,
              const int* __restrict__ src_ids, const float* __restrict__ gi_dec,
              const float* __restrict__ wih0, const float* __restrict__ whh0,
              const float* __restrict__ bhh0,
              const float* __restrict__ wih1, const float* __restrict__ bih1,
              const float* __restrict__ whh1, const float* __restrict__ bhh1,
              float* __restrict__ cat,
              const float* __restrict__ h0init, const float* __restrict__ h1init,
              float* __restrict__ h0seq, float* __restrict__ h1seq,
              float* __restrict__ scrseq, unsigned* cnt)
{
    __shared__ float sm[2 * 2 * 3 * 8 * 32];   // 12 KB, gru phases
    __shared__ float at[S_];
    __shared__ float red4[4][64];
    const int blk = blockIdx.x, tid = threadIdx.x;
    unsigned tgt = 0;
    for (int t = 0; t < T_ - 1; ++t) {
        const float* d1p = t ? h1seq + (long)(t - 1) * B_ * H_ : h1init;
        const float* h0p = t ? h0seq + (long)(t - 1) * B_ * H_ : h0init;
        float* scr = scrseq + (long)t * (B_ * S_);
        // ---- A1: scores[b][s] = proj[b,s,:] . d1[b,:]  (16 blocks/b, 4 s each)
        {
            const int b    = blk >> 4;
            const int s    = ((blk & 15) << 2) + (tid >> 6);
            const int lane = tid & 63;
            const float* pr = proj + ((long)b * S_ + s) * H_;
            const float* dr = d1p + (long)b * H_;
            float a = 0.f;
#pragma unroll
            for (int c = 0; c < 4; ++c) {
                float4 pv = *(const float4*)(pr + c * 256 + lane * 4);
                float4 dv = *(const float4*)(dr + c * 256 + lane * 4);
                a += pv.x*dv.x + pv.y*dv.y + pv.z*dv.z + pv.w*dv.w;
            }
#pragma unroll
            for (int off = 32; off > 0; off >>= 1) a += __shfl_xor(a, off);
            if (lane == 0)
                coh_store(&scr[b * S_ + s], (src_ids[b * S_ + s] != 0) ? a : -1e9f);
        }
        gsync(cnt, 512, tgt);
        // ---- A2: softmax (redundant per block) + ctx 64-h slice
        {
            const int b  = blk >> 4;
            const int hs = (blk & 15) * 64;
            if (tid < 64) {
                float v = scr[b * S_ + tid];
                float mx = v;
#pragma unroll
                for (int off = 32; off > 0; off >>= 1) mx = fmaxf(mx, __shfl_xor(mx, off));
                float e = expf(v - mx);
                float smm = e;
#pragma unroll
                for (int off = 32; off > 0; off >>= 1) smm += __shfl_xor(smm, off);
                at[tid] = e / smm;
            }
            __syncthreads();
            const int h  = hs + (tid & 63);
            const int sg = tid >> 6;
            const float* eb = enc_out + (long)b * S_ * H_ + h;
            float a = 0.f;
            for (int s = sg * 16; s < sg * 16 + 16; ++s)
                a += at[s] * eb[(long)s * H_];
            red4[sg][tid & 63] = a;
            __syncthreads();
            if (tid < 64)
                coh_store(&cat[(long)t * B_ * 2048 + (long)b * 2048 + H_ + hs + tid],
                          red4[0][tid] + red4[1][tid] + red4[2][tid] + red4[3][tid]);
        }
        gsync(cnt, 512, tgt);
        // ---- C: gru0 (x = ctx, gi precomputed)
        gru_phase<1, 1>(sm, blk * 2,
                        cat + (long)t * B_ * 2048 + H_, 2048,
                        wih0, E_ + H_, E_, nullptr,
                        gi_dec + (long)t * B_ * G3,
                        h0p, H_, whh0, bhh0,
                        h0seq + (long)t * B_ * H_, H_, nullptr, 0);
        gsync(cnt, 512, tgt);
        // ---- D: gru1 (x = h0_new), write d1 into cat row
        gru_phase<1, 0>(sm, blk * 2,
                        h0seq + (long)t * B_ * H_, H_,
                        wih1, H_, 0, bih1, nullptr,
                        d1p, H_, whh1, bhh1,
                        h1seq + (long)t * B_ * H_, H_,
                        cat + (long)t * B_ * 2048, 2048);
        if (t < T_ - 2) gsync(cnt, 512, tgt);
    }
}

// ---------------------------------------------------------------------------
extern "C" void kernel_launch(void* const* d_in, const int* in_sizes, int n_in,
                              void* d_out, int out_size, void* d_ws, size_t ws_size,
                              hipStream_t stream)
{
    (void)in_sizes; (void)n_in; (void)out_size; (void)ws_size;
    const int*   src_ids  = (const int*)  d_in[0];
    const int*   tgt_ids  = (const int*)  d_in[2];
    const float* enc_emb  = (const float*)d_in[3];
    const float* dec_emb  = (const float*)d_in[4];
    const float* enc_wih0 = (const float*)d_in[5];
    const float* enc_whh0 = (const float*)d_in[6];
    const float* enc_bih0 = (const float*)d_in[7];
    const float* enc_bhh0 = (const float*)d_in[8];
    const float* enc_wih1 = (const float*)d_in[9];
    const float* enc_whh1 = (const float*)d_in[10];
    const float* enc_bih1 = (const float*)d_in[11];
    const float* enc_bhh1 = (const float*)d_in[12];
    const float* dec_wih0 = (const float*)d_in[13];
    const float* dec_whh0 = (const float*)d_in[14];
    const float* dec_bih0 = (const float*)d_in[15];
    const float* dec_bhh0 = (const float*)d_in[16];
    const float* dec_wih1 = (const float*)d_in[17];
    const float* dec_whh1 = (const float*)d_in[18];
    const float* dec_bih1 = (const float*)d_in[19];
    const float* dec_bhh1 = (const float*)d_in[20];
    const float* attn_w   = (const float*)d_in[21];
    const float* out_w    = (const float*)d_in[22];
    const float* out_b    = (const float*)d_in[23];
    float* out = (float*)d_out;

    // workspace layout (floats)
    float* ws      = (float*)d_ws;
    float* gi_enc0 = ws;                         // 2048*3072 (reused: gi_enc1, then dec state seqs)
    float* gi_dec  = gi_enc0 + 2048L * G3;       // 1536*3072
    float* enc_out = gi_dec  + 1536L * G3;       // 2048*1024  [b][s][h]
    float* proj    = enc_out + 2048L * H_;       // 2048*1024  [b][s][h]
    float* cat     = proj    + 2048L * H_;       // 1536*2048  row m=t*32+b: [d1 | ctx]
    float* states  = cat     + 1536L * 2048;     // 4*32*1024
    unsigned* cnts = (unsigned*)(states + 4L * B_ * H_);  // 64 u32 (3 slots, 64B apart)
    float* z0      = states;                     // zeros: enc l0 initial h
    float* h0fin   = states + 1L * B_ * H_;      // enc l0 final h -> dec init h0
    float* z1      = states + 2L * B_ * H_;      // zeros: enc l1 initial h
    float* h1fin   = states + 3L * B_ * H_;      // enc l1 final h -> dec init h1
    float* enc_l0  = cat;                        // alias: layer-0 seq [t][b][h], free pre-decoder
    // dec rotated state (inside gi_enc0, free during decoder): 47-step seqs
    float* h0seq   = gi_enc0;                    // 47*32*1024
    float* h1seq   = gi_enc0 + 1600L * 1024;     // 47*32*1024
    float* scrseq  = gi_enc0 + 3300L * 1024;     // 47*2048

    // zero states + sync counters (re-zeroed on every graph replay)
    hipMemsetAsync(states, 0, (4L * B_ * H_ + 64) * sizeof(float), stream);

    // batched input-to-hidden GEMMs (embedding gather fused)
    gemm_mfma<<<dim3(24, 16), 256, 0, stream>>>(enc_emb, E_, src_ids, 1, enc_wih0, E_, enc_bih0,
                                                gi_enc0, 0, G3, 2048, E_);
    gemm_mfma<<<dim3(24, 12), 256, 0, stream>>>(dec_emb, E_, tgt_ids, 2, dec_wih0, E_ + H_, dec_bih0,
                                                gi_dec, 0, G3, 1536, E_);

    // ---- encoder layer 0 (persistent, 64 steps in one launch) ----
    enc_loop<<<512, 256, 0, stream>>>(gi_enc0, enc_whh0, enc_bhh0, z0,
                                      enc_l0, (long)B_ * H_, (long)H_, h0fin, S_, cnts + 0);

    // batched layer-1 input GEMM: gi_enc1 = enc_l0 @ wih1.T  (overwrites gi_enc0)
    gemm_mfma<<<dim3(24, 16), 256, 0, stream>>>(enc_l0, H_, nullptr, 0, enc_wih1, H_, enc_bih1,
                                                gi_enc0, 0, G3, 2048, H_);

    // ---- encoder layer 1 (persistent) ----
    enc_loop<<<512, 256, 0, stream>>>(gi_enc0, enc_whh1, enc_bhh1, z1,
                                      enc_out, (long)H_, (long)S_ * H_, h1fin, S_, cnts + 16);

    // proj = enc_out @ attn_w.T   (M=2048, N=1024, K=1024)
    gemm_mfma<<<dim3(8, 16), 256, 0, stream>>>(enc_out, H_, nullptr, 0, attn_w, H_, nullptr,
                                               proj, 0, H_, 2048, H_);

    // ---- decoder (persistent, all 47 steps in one launch) ----
    dec_loop<<<512, 256, 0, stream>>>(proj, enc_out, src_ids, gi_dec,
                                      dec_wih0, dec_whh0, dec_bhh0,
                                      dec_wih1, dec_bih1, dec_whh1, dec_bhh1,
                                      cat, h0fin, h1fin, h0seq, h1seq, scrseq, cnts + 32);

    // ---- output projection: out = cat @ out_w.T + out_b ----
    gemm_mfma<<<dim3(V_ / 128, 12), 256, 0, stream>>>(cat, 2048, nullptr, 0, out_w, 2048, out_b,
                                                      out, 1, 0, 1504, 2048);
}